// Round 2
// baseline (397.379 us; speedup 1.0000x reference)
//
#include <hip/hip_runtime.h>
#include <hip/hip_bf16.h>

#define NUM_C 1000
#define DIM   128
#define MM    64
#define BB    64
#define LL    512
#define NROWS (BB * LL)   // 32768

__device__ __forceinline__ float sigmoidf_fast(float x) { return 1.f / (1.f + __expf(-x)); }
__device__ __forceinline__ float tanhf_fast(float x) { return 1.f - 2.f / (__expf(2.f * x) + 1.f); }

// ---------------------------------------------------------------------------
// Kernel A: w[b,l,m] = softmax_m( k . Mk[m] ),  k = Ek[q[b,l]]
// 128 threads (2 waves), each wave handles one row per iteration; MkT in LDS
// with +1-pad stride 65 (conflict-free on both store and read).
// ---------------------------------------------------------------------------
__global__ __launch_bounds__(128) void kA(const int* __restrict__ q,
                                          const float* __restrict__ Ek,
                                          const float* __restrict__ Mk,
                                          float* __restrict__ w_out) {
    __shared__ float MkT[DIM * 65];
    __shared__ float kbuf[2][DIM];
    const int tid = threadIdx.x;

    // stage Mk transposed: MkT[i*65 + m] = Mk[m][i]
    #pragma unroll
    for (int it = 0; it < 64; ++it) {
        int idx = it * 128 + tid;
        int m = idx >> 7, i = idx & 127;
        MkT[i * 65 + m] = Mk[m * DIM + i];
    }
    __syncthreads();

    const int wv = tid >> 6;      // which of 2 rows
    const int lane = tid & 63;    // m index
    const int base = blockIdx.x * 32;

    for (int it = 0; it < 16; ++it) {
        int rr = base + it * 2 + wv;
        int qv = q[rr];
        kbuf[wv][lane]      = Ek[(size_t)qv * DIM + lane];
        kbuf[wv][lane + 64] = Ek[(size_t)qv * DIM + lane + 64];
        __syncthreads();

        float s = 0.f;
        #pragma unroll 8
        for (int i = 0; i < DIM; ++i)
            s = fmaf(kbuf[wv][i], MkT[i * 65 + lane], s);

        // softmax over the 64 lanes of this wave
        float mx = s;
        #pragma unroll
        for (int o = 32; o >= 1; o >>= 1) mx = fmaxf(mx, __shfl_xor(mx, o));
        float ex = __expf(s - mx);
        float sum = ex;
        #pragma unroll
        for (int o = 32; o >= 1; o >>= 1) sum += __shfl_xor(sum, o);

        w_out[(size_t)rr * MM + lane] = ex / sum;
        __syncthreads();
    }
}

// ---------------------------------------------------------------------------
// Kernel B: e = sigmoid(v@We+be), a = tanh(v@Wa+ba),  v = Ev[q+1000*r]
// 128 threads, 8 rows per block; v transposed in LDS -> 2x ds_read_b128 per i.
// ---------------------------------------------------------------------------
__global__ __launch_bounds__(128) void kB(const int* __restrict__ q,
                                          const int* __restrict__ r,
                                          const float* __restrict__ Ev,
                                          const float* __restrict__ We,
                                          const float* __restrict__ be,
                                          const float* __restrict__ Wa,
                                          const float* __restrict__ ba,
                                          float* __restrict__ e_out,
                                          float* __restrict__ a_out) {
    __shared__ __align__(16) float vbufT[DIM][8];
    const int tid = threadIdx.x;
    const int base = blockIdx.x * 8;

    #pragma unroll
    for (int rr = 0; rr < 8; ++rr) {
        int row = base + rr;
        int x = q[row] + NUM_C * r[row];
        vbufT[tid][rr] = Ev[(size_t)x * DIM + tid];
    }
    __syncthreads();

    float eacc[8], aacc[8];
    #pragma unroll
    for (int rr = 0; rr < 8; ++rr) { eacc[rr] = 0.f; aacc[rr] = 0.f; }

    for (int i = 0; i < DIM; ++i) {
        float we = We[i * DIM + tid];
        float wa = Wa[i * DIM + tid];
        const float4* vp = reinterpret_cast<const float4*>(&vbufT[i][0]);
        float4 v0 = vp[0], v1 = vp[1];
        float vr[8] = {v0.x, v0.y, v0.z, v0.w, v1.x, v1.y, v1.z, v1.w};
        #pragma unroll
        for (int rr = 0; rr < 8; ++rr) {
            eacc[rr] = fmaf(vr[rr], we, eacc[rr]);
            aacc[rr] = fmaf(vr[rr], wa, aacc[rr]);
        }
    }

    float bev = be[tid], bav = ba[tid];
    #pragma unroll
    for (int rr = 0; rr < 8; ++rr) {
        int row = base + rr;
        e_out[(size_t)row * DIM + tid] = sigmoidf_fast(eacc[rr] + bev);
        a_out[(size_t)row * DIM + tid] = tanhf_fast(aacc[rr] + bav);
    }
}

// ---------------------------------------------------------------------------
// Kernel C: the scan. Block (g,b) owns m-slice [g*NG, g*NG+NG).
// 256 threads: thread t -> d = t>>1, half p = t&1 owning JJ=NG/2 m's.
// Mv in registers; per-step w/e/a loads prefetched PF steps ahead.
// partial[(g*BB+b)*LL + t][d] = sum over this block's m of w*Mv (pre-update).
// ---------------------------------------------------------------------------
template <int NG>
__global__ __launch_bounds__(256) void kC(const float* __restrict__ Mv0,
                                          const float* __restrict__ w_in,
                                          const float* __restrict__ e_in,
                                          const float* __restrict__ a_in,
                                          float* __restrict__ partial) {
    constexpr int JJ = NG / 2;
    constexpr int PF = (JJ > 8) ? 2 : 4;   // prefetch depth; LL % PF == 0
    const int tid = threadIdx.x;
    const int p = tid & 1;
    const int d = tid >> 1;
    const int g = blockIdx.x, b = blockIdx.y;
    const int m0 = g * NG + p * JJ;

    float Mv[JJ];
    #pragma unroll
    for (int j = 0; j < JJ; ++j)
        Mv[j] = Mv0[(m0 + j) * DIM + d];

    const float* wp = w_in + (size_t)b * LL * MM + m0;
    const float* ep = e_in + (size_t)b * LL * DIM + d;
    const float* ap = a_in + (size_t)b * LL * DIM + d;
    float* pr = partial + ((size_t)(g * BB + b) * LL) * DIM + d;

    float eb[PF], ab[PF], wb[PF][JJ];
    #pragma unroll
    for (int u = 0; u < PF; ++u) {
        eb[u] = ep[(size_t)u * DIM];
        ab[u] = ap[(size_t)u * DIM];
        #pragma unroll
        for (int j4 = 0; j4 < JJ / 4; ++j4) {
            float4 t4 = *reinterpret_cast<const float4*>(wp + (size_t)u * MM + j4 * 4);
            wb[u][j4 * 4 + 0] = t4.x; wb[u][j4 * 4 + 1] = t4.y;
            wb[u][j4 * 4 + 2] = t4.z; wb[u][j4 * 4 + 3] = t4.w;
        }
    }

    for (int t0 = 0; t0 < LL; t0 += PF) {
        #pragma unroll
        for (int u = 0; u < PF; ++u) {
            const int t = t0 + u;
            float e_c = eb[u], a_c = ab[u];
            float part = 0.f;
            #pragma unroll
            for (int j = 0; j < JJ; ++j) {
                float wv = wb[u][j];
                float old = Mv[j];
                part = fmaf(wv, old, part);              // read BEFORE update
                float t1 = fmaf(-old, e_c, a_c);         // a - e*Mv
                Mv[j] = fmaf(wv, t1, old);               // Mv + w*(a - e*Mv)
            }
            part += __shfl_xor(part, 1);
            if (p == 0) pr[(size_t)t * DIM] = part;

            if (t + PF < LL) {
                eb[u] = ep[(size_t)(t + PF) * DIM];
                ab[u] = ap[(size_t)(t + PF) * DIM];
                #pragma unroll
                for (int j4 = 0; j4 < JJ / 4; ++j4) {
                    float4 t4 = *reinterpret_cast<const float4*>(wp + (size_t)(t + PF) * MM + j4 * 4);
                    wb[u][j4 * 4 + 0] = t4.x; wb[u][j4 * 4 + 1] = t4.y;
                    wb[u][j4 * 4 + 2] = t4.z; wb[u][j4 * 4 + 3] = t4.w;
                }
            }
        }
    }
}

// ---------------------------------------------------------------------------
// Kernel D: read = sum_g partial; f = tanh([read,k]@Wf + bf); p = sigmoid(f@Wp+bp)
// 128 threads, 8 rows per block; x transposed in LDS.
// ---------------------------------------------------------------------------
__global__ __launch_bounds__(128) void kD(const int* __restrict__ q,
                                          const float* __restrict__ Ek,
                                          const float* __restrict__ Wf,
                                          const float* __restrict__ bfv,
                                          const float* __restrict__ Wp,
                                          const float* __restrict__ bp,
                                          const float* __restrict__ partial,
                                          int G,
                                          float* __restrict__ out) {
    __shared__ __align__(16) float xbufT[2 * DIM][8];
    __shared__ float fbuf[8][DIM];
    __shared__ float sbuf[8][8];
    const int tid = threadIdx.x;
    const int base = blockIdx.x * 8;

    #pragma unroll
    for (int rr = 0; rr < 8; ++rr) {
        int row = base + rr;
        float rd = 0.f;
        for (int g = 0; g < G; ++g)
            rd += partial[(size_t)g * NROWS * DIM + (size_t)row * DIM + tid];
        xbufT[tid][rr] = rd;
        xbufT[DIM + tid][rr] = Ek[(size_t)q[row] * DIM + tid];
    }
    __syncthreads();

    float facc[8];
    #pragma unroll
    for (int rr = 0; rr < 8; ++rr) facc[rr] = 0.f;

    for (int i = 0; i < 2 * DIM; ++i) {
        float wf = Wf[i * DIM + tid];
        const float4* xp = reinterpret_cast<const float4*>(&xbufT[i][0]);
        float4 x0 = xp[0], x1 = xp[1];
        float xr[8] = {x0.x, x0.y, x0.z, x0.w, x1.x, x1.y, x1.z, x1.w};
        #pragma unroll
        for (int rr = 0; rr < 8; ++rr)
            facc[rr] = fmaf(xr[rr], wf, facc[rr]);
    }

    float bfs = bfv[tid];
    float wpv = Wp[tid];
    #pragma unroll
    for (int rr = 0; rr < 8; ++rr)
        fbuf[rr][tid] = tanhf_fast(facc[rr] + bfs) * wpv;
    __syncthreads();

    if (tid < 64) {
        int rr = tid >> 3, j = tid & 7;
        float s = 0.f;
        #pragma unroll
        for (int i = 0; i < 16; ++i) s += fbuf[rr][j + 8 * i];
        sbuf[rr][j] = s;
    }
    __syncthreads();
    if (tid < 8) {
        float s = bp[0];
        #pragma unroll
        for (int j = 0; j < 8; ++j) s += sbuf[tid][j];
        out[base + tid] = sigmoidf_fast(s);
    }
}

// ---------------------------------------------------------------------------
extern "C" void kernel_launch(void* const* d_in, const int* in_sizes, int n_in,
                              void* d_out, int out_size, void* d_ws, size_t ws_size,
                              hipStream_t stream) {
    const int*   q   = (const int*)d_in[0];
    const int*   r   = (const int*)d_in[1];
    const float* Ek  = (const float*)d_in[2];
    const float* Ev  = (const float*)d_in[3];
    const float* Mk  = (const float*)d_in[4];
    const float* Mv0 = (const float*)d_in[5];
    const float* We  = (const float*)d_in[6];
    const float* be  = (const float*)d_in[7];
    const float* Wa  = (const float*)d_in[8];
    const float* ba  = (const float*)d_in[9];
    const float* Wf  = (const float*)d_in[10];
    const float* bfv = (const float*)d_in[11];
    const float* Wp  = (const float*)d_in[12];
    const float* bp  = (const float*)d_in[13];
    float* out = (float*)d_out;

    float* ws    = (float*)d_ws;
    float* w_buf = ws;                                   // NROWS*64  floats
    float* e_buf = ws + (size_t)NROWS * MM;              // NROWS*128 floats
    float* a_buf = e_buf + (size_t)NROWS * DIM;          // NROWS*128 floats
    float* part  = a_buf + (size_t)NROWS * DIM;          // G * NROWS*128 floats

    // pick largest m-split G that fits in the workspace
    const size_t base_floats = (size_t)NROWS * MM + 2ull * NROWS * DIM;
    int G = 4;
    while (G > 1 && (base_floats + (size_t)G * NROWS * DIM) * 4ull > ws_size) G >>= 1;

    kA<<<dim3(NROWS / 32), 128, 0, stream>>>(q, Ek, Mk, w_buf);
    kB<<<dim3(NROWS / 8), 128, 0, stream>>>(q, r, Ev, We, be, Wa, ba, e_buf, a_buf);

    if (G == 4)      kC<16><<<dim3(4, BB), 256, 0, stream>>>(Mv0, w_buf, e_buf, a_buf, part);
    else if (G == 2) kC<32><<<dim3(2, BB), 256, 0, stream>>>(Mv0, w_buf, e_buf, a_buf, part);
    else             kC<64><<<dim3(1, BB), 256, 0, stream>>>(Mv0, w_buf, e_buf, a_buf, part);

    kD<<<dim3(NROWS / 8), 128, 0, stream>>>(q, Ek, Wf, bfv, Wp, bp, part, G, out);
}

// Round 3
// 343.331 us; speedup vs baseline: 1.1574x; 1.1574x over previous
//
#include <hip/hip_runtime.h>
#include <hip/hip_bf16.h>

#define NUM_C 1000
#define DIM   128
#define MM    64
#define BB    64
#define LL    512
#define NROWS (BB * LL)   // 32768

__device__ __forceinline__ float sigmoidf_fast(float x) { return 1.f / (1.f + __expf(-x)); }
__device__ __forceinline__ float tanhf_fast(float x) { return 1.f - 2.f / (__expf(2.f * x) + 1.f); }

// VALU-only neighbor-pair swap (lanes 0<->1, 2<->3, ...): DPP quad_perm(1,0,3,2)
__device__ __forceinline__ float swap_pair(float x) {
    int yi = __builtin_amdgcn_mov_dpp(__float_as_int(x), 0xB1, 0xF, 0xF, true);
    return __int_as_float(yi);
}

// ---------------------------------------------------------------------------
// Kernel A: w[b,l,m] = softmax_m( k . Mk[m] ),  k = Ek[q[b,l]]
// ---------------------------------------------------------------------------
__global__ __launch_bounds__(128) void kA(const int* __restrict__ q,
                                          const float* __restrict__ Ek,
                                          const float* __restrict__ Mk,
                                          float* __restrict__ w_out) {
    __shared__ float MkT[DIM * 65];
    __shared__ float kbuf[2][DIM];
    const int tid = threadIdx.x;

    #pragma unroll
    for (int it = 0; it < 64; ++it) {
        int idx = it * 128 + tid;
        int m = idx >> 7, i = idx & 127;
        MkT[i * 65 + m] = Mk[m * DIM + i];
    }
    __syncthreads();

    const int wv = tid >> 6;
    const int lane = tid & 63;
    const int base = blockIdx.x * 32;

    for (int it = 0; it < 16; ++it) {
        int rr = base + it * 2 + wv;
        int qv = q[rr];
        kbuf[wv][lane]      = Ek[(size_t)qv * DIM + lane];
        kbuf[wv][lane + 64] = Ek[(size_t)qv * DIM + lane + 64];
        __syncthreads();

        float s = 0.f;
        #pragma unroll 8
        for (int i = 0; i < DIM; ++i)
            s = fmaf(kbuf[wv][i], MkT[i * 65 + lane], s);

        float mx = s;
        #pragma unroll
        for (int o = 32; o >= 1; o >>= 1) mx = fmaxf(mx, __shfl_xor(mx, o));
        float ex = __expf(s - mx);
        float sum = ex;
        #pragma unroll
        for (int o = 32; o >= 1; o >>= 1) sum += __shfl_xor(sum, o);

        w_out[(size_t)rr * MM + lane] = ex / sum;
        __syncthreads();
    }
}

// ---------------------------------------------------------------------------
// Kernel B: e = sigmoid(v@We+be), a = tanh(v@Wa+ba),  v = Ev[q+1000*r]
// 128 threads, 16 rows per block; v transposed in LDS, stride 20 (16B-aligned
// rows, 8-way write conflict only on the tiny staging phase).
// ---------------------------------------------------------------------------
__global__ __launch_bounds__(128) void kB(const int* __restrict__ q,
                                          const int* __restrict__ r,
                                          const float* __restrict__ Ev,
                                          const float* __restrict__ We,
                                          const float* __restrict__ be,
                                          const float* __restrict__ Wa,
                                          const float* __restrict__ ba,
                                          float* __restrict__ e_out,
                                          float* __restrict__ a_out) {
    __shared__ __align__(16) float vbufT[DIM][20];
    const int tid = threadIdx.x;
    const int base = blockIdx.x * 16;

    #pragma unroll
    for (int rr = 0; rr < 16; ++rr) {
        int row = base + rr;
        int x = q[row] + NUM_C * r[row];
        vbufT[tid][rr] = Ev[(size_t)x * DIM + tid];
    }
    __syncthreads();

    float eacc[16], aacc[16];
    #pragma unroll
    for (int rr = 0; rr < 16; ++rr) { eacc[rr] = 0.f; aacc[rr] = 0.f; }

    #pragma unroll 4
    for (int i = 0; i < DIM; ++i) {
        float we = We[i * DIM + tid];
        float wa = Wa[i * DIM + tid];
        const float4* vp = reinterpret_cast<const float4*>(&vbufT[i][0]);
        float4 v0 = vp[0], v1 = vp[1], v2 = vp[2], v3 = vp[3];
        float vr[16] = {v0.x, v0.y, v0.z, v0.w, v1.x, v1.y, v1.z, v1.w,
                        v2.x, v2.y, v2.z, v2.w, v3.x, v3.y, v3.z, v3.w};
        #pragma unroll
        for (int rr = 0; rr < 16; ++rr) {
            eacc[rr] = fmaf(vr[rr], we, eacc[rr]);
            aacc[rr] = fmaf(vr[rr], wa, aacc[rr]);
        }
    }

    float bev = be[tid], bav = ba[tid];
    #pragma unroll
    for (int rr = 0; rr < 16; ++rr) {
        int row = base + rr;
        e_out[(size_t)row * DIM + tid] = sigmoidf_fast(eacc[rr] + bev);
        a_out[(size_t)row * DIM + tid] = tanhf_fast(aacc[rr] + bav);
    }
}

// ---------------------------------------------------------------------------
// Kernel C: the scan, LDS-tiled. Block (g,b) owns m-slice [g*NG, g*NG+NG).
// T=32 steps staged per tile (w: all 64 m, e, a), double-buffered; next tile's
// loads issued before scanning current tile (~1600 cyc latency cover).
// 256 threads: thread t -> d = t>>1, half p = t&1 owning JJ=NG/2 m's.
// ---------------------------------------------------------------------------
template <int NG>
__global__ __launch_bounds__(256) void kC(const float* __restrict__ Mv0,
                                          const float* __restrict__ w_in,
                                          const float* __restrict__ e_in,
                                          const float* __restrict__ a_in,
                                          float* __restrict__ partial) {
    constexpr int JJ = NG / 2;
    constexpr int T = 32;           // steps per tile
    constexpr int NTILE = LL / T;   // 16

    __shared__ __align__(16) float wT[2][T][MM];    // 16 KB
    __shared__ __align__(16) float eT[2][T][DIM];   // 32 KB
    __shared__ __align__(16) float aT[2][T][DIM];   // 32 KB

    const int tid = threadIdx.x;
    const int p = tid & 1;
    const int d = tid >> 1;
    const int g = blockIdx.x, b = blockIdx.y;
    const int m0 = g * NG + p * JJ;   // global m index of this thread's slice

    float Mv[JJ];
    #pragma unroll
    for (int j = 0; j < JJ; ++j)
        Mv[j] = Mv0[(m0 + j) * DIM + d];

    const float4* wsrc = reinterpret_cast<const float4*>(w_in + (size_t)b * LL * MM);
    const float4* esrc = reinterpret_cast<const float4*>(e_in + (size_t)b * LL * DIM);
    const float4* asrc = reinterpret_cast<const float4*>(a_in + (size_t)b * LL * DIM);
    float* pr = partial + ((size_t)(g * BB + b) * LL) * DIM + d;

    // per-tile flat float4 counts: w: T*MM/4 = 512 (2/thread), e,a: T*DIM/4 = 1024 (4/thread)
    float4 wreg[2], ereg[4], areg[4];

    // prologue: tile 0
    {
        const int t4 = 0;
        wreg[0] = wsrc[t4 * (T * MM / 4) + tid];
        wreg[1] = wsrc[t4 * (T * MM / 4) + tid + 256];
        #pragma unroll
        for (int k = 0; k < 4; ++k) {
            ereg[k] = esrc[t4 * (T * DIM / 4) + tid + k * 256];
            areg[k] = asrc[t4 * (T * DIM / 4) + tid + k * 256];
        }
        float4* wd = reinterpret_cast<float4*>(&wT[0][0][0]);
        float4* ed = reinterpret_cast<float4*>(&eT[0][0][0]);
        float4* ad = reinterpret_cast<float4*>(&aT[0][0][0]);
        wd[tid] = wreg[0]; wd[tid + 256] = wreg[1];
        #pragma unroll
        for (int k = 0; k < 4; ++k) { ed[tid + k * 256] = ereg[k]; ad[tid + k * 256] = areg[k]; }
    }
    __syncthreads();

    int buf = 0;
    for (int c = 0; c < NTILE; ++c) {
        // issue next tile's global loads (land in regs while we scan)
        if (c + 1 < NTILE) {
            const int off_w = (c + 1) * (T * MM / 4);
            const int off_e = (c + 1) * (T * DIM / 4);
            wreg[0] = wsrc[off_w + tid];
            wreg[1] = wsrc[off_w + tid + 256];
            #pragma unroll
            for (int k = 0; k < 4; ++k) {
                ereg[k] = esrc[off_e + tid + k * 256];
                areg[k] = asrc[off_e + tid + k * 256];
            }
        }

        // scan T steps from LDS buf
        #pragma unroll 4
        for (int u = 0; u < T; ++u) {
            const int t = c * T + u;
            float e_c = eT[buf][u][d];
            float a_c = aT[buf][u][d];
            float part = 0.f;
            #pragma unroll
            for (int j4 = 0; j4 < JJ / 4; ++j4) {
                float4 w4 = *reinterpret_cast<const float4*>(&wT[buf][u][m0 + j4 * 4]);
                float wv[4] = {w4.x, w4.y, w4.z, w4.w};
                #pragma unroll
                for (int jj = 0; jj < 4; ++jj) {
                    int j = j4 * 4 + jj;
                    float old = Mv[j];
                    part = fmaf(wv[jj], old, part);           // read BEFORE update
                    float t1 = fmaf(-old, e_c, a_c);          // a - e*Mv
                    Mv[j] = fmaf(wv[jj], t1, old);            // Mv + w*(a - e*Mv)
                }
            }
            part += swap_pair(part);
            if (p == 0) pr[(size_t)t * DIM] = part;
        }

        // stage next tile into the other buffer; single barrier per tile
        if (c + 1 < NTILE) {
            float4* wd = reinterpret_cast<float4*>(&wT[buf ^ 1][0][0]);
            float4* ed = reinterpret_cast<float4*>(&eT[buf ^ 1][0][0]);
            float4* ad = reinterpret_cast<float4*>(&aT[buf ^ 1][0][0]);
            wd[tid] = wreg[0]; wd[tid + 256] = wreg[1];
            #pragma unroll
            for (int k = 0; k < 4; ++k) { ed[tid + k * 256] = ereg[k]; ad[tid + k * 256] = areg[k]; }
            __syncthreads();
            buf ^= 1;
        }
    }
}

// ---------------------------------------------------------------------------
// Kernel D: read = sum_g partial; f = tanh([read,k]@Wf + bf); p = sigmoid(f@Wp+bp)
// 128 threads, 16 rows per block; x transposed in LDS stride 20.
// ---------------------------------------------------------------------------
__global__ __launch_bounds__(128) void kD(const int* __restrict__ q,
                                          const float* __restrict__ Ek,
                                          const float* __restrict__ Wf,
                                          const float* __restrict__ bfv,
                                          const float* __restrict__ Wp,
                                          const float* __restrict__ bp,
                                          const float* __restrict__ partial,
                                          int G,
                                          float* __restrict__ out) {
    __shared__ __align__(16) float xbufT[2 * DIM][20];
    __shared__ float fbuf[16][DIM];
    __shared__ float sbuf[16][8];
    const int tid = threadIdx.x;
    const int base = blockIdx.x * 16;

    #pragma unroll
    for (int rr = 0; rr < 16; ++rr) {
        int row = base + rr;
        float rd = 0.f;
        for (int g = 0; g < G; ++g)
            rd += partial[(size_t)g * NROWS * DIM + (size_t)row * DIM + tid];
        xbufT[tid][rr] = rd;
        xbufT[DIM + tid][rr] = Ek[(size_t)q[row] * DIM + tid];
    }
    __syncthreads();

    float facc[16];
    #pragma unroll
    for (int rr = 0; rr < 16; ++rr) facc[rr] = 0.f;

    #pragma unroll 4
    for (int i = 0; i < 2 * DIM; ++i) {
        float wf = Wf[i * DIM + tid];
        const float4* xp = reinterpret_cast<const float4*>(&xbufT[i][0]);
        float4 x0 = xp[0], x1 = xp[1], x2 = xp[2], x3 = xp[3];
        float xr[16] = {x0.x, x0.y, x0.z, x0.w, x1.x, x1.y, x1.z, x1.w,
                        x2.x, x2.y, x2.z, x2.w, x3.x, x3.y, x3.z, x3.w};
        #pragma unroll
        for (int rr = 0; rr < 16; ++rr)
            facc[rr] = fmaf(xr[rr], wf, facc[rr]);
    }

    float bfs = bfv[tid];
    float wpv = Wp[tid];
    #pragma unroll
    for (int rr = 0; rr < 16; ++rr)
        fbuf[rr][tid] = tanhf_fast(facc[rr] + bfs) * wpv;
    __syncthreads();

    {
        int rr = tid >> 3, j = tid & 7;   // all 128 threads
        float s = 0.f;
        #pragma unroll
        for (int i = 0; i < 16; ++i) s += fbuf[rr][j + 8 * i];
        sbuf[rr][j] = s;
    }
    __syncthreads();
    if (tid < 16) {
        float s = bp[0];
        #pragma unroll
        for (int j = 0; j < 8; ++j) s += sbuf[tid][j];
        out[base + tid] = sigmoidf_fast(s);
    }
}

// ---------------------------------------------------------------------------
extern "C" void kernel_launch(void* const* d_in, const int* in_sizes, int n_in,
                              void* d_out, int out_size, void* d_ws, size_t ws_size,
                              hipStream_t stream) {
    const int*   q   = (const int*)d_in[0];
    const int*   r   = (const int*)d_in[1];
    const float* Ek  = (const float*)d_in[2];
    const float* Ev  = (const float*)d_in[3];
    const float* Mk  = (const float*)d_in[4];
    const float* Mv0 = (const float*)d_in[5];
    const float* We  = (const float*)d_in[6];
    const float* be  = (const float*)d_in[7];
    const float* Wa  = (const float*)d_in[8];
    const float* ba  = (const float*)d_in[9];
    const float* Wf  = (const float*)d_in[10];
    const float* bfv = (const float*)d_in[11];
    const float* Wp  = (const float*)d_in[12];
    const float* bp  = (const float*)d_in[13];
    float* out = (float*)d_out;

    float* ws    = (float*)d_ws;
    float* w_buf = ws;                                   // NROWS*64  floats
    float* e_buf = ws + (size_t)NROWS * MM;              // NROWS*128 floats
    float* a_buf = e_buf + (size_t)NROWS * DIM;          // NROWS*128 floats
    float* part  = a_buf + (size_t)NROWS * DIM;          // G * NROWS*128 floats

    const size_t base_floats = (size_t)NROWS * MM + 2ull * NROWS * DIM;
    int G = 4;
    while (G > 1 && (base_floats + (size_t)G * NROWS * DIM) * 4ull > ws_size) G >>= 1;

    kA<<<dim3(NROWS / 32), 128, 0, stream>>>(q, Ek, Mk, w_buf);
    kB<<<dim3(NROWS / 16), 128, 0, stream>>>(q, r, Ev, We, be, Wa, ba, e_buf, a_buf);

    if (G == 4)      kC<16><<<dim3(4, BB), 256, 0, stream>>>(Mv0, w_buf, e_buf, a_buf, part);
    else if (G == 2) kC<32><<<dim3(2, BB), 256, 0, stream>>>(Mv0, w_buf, e_buf, a_buf, part);
    else             kC<64><<<dim3(1, BB), 256, 0, stream>>>(Mv0, w_buf, e_buf, a_buf, part);

    kD<<<dim3(NROWS / 16), 128, 0, stream>>>(q, Ek, Wf, bfv, Wp, bp, part, G, out);
}

// Round 4
// 295.723 us; speedup vs baseline: 1.3438x; 1.1610x over previous
//
#include <hip/hip_runtime.h>
#include <hip/hip_bf16.h>

#define NUM_C 1000
#define DIM   128
#define MM    64
#define BB    64
#define LL    512
#define NROWS (BB * LL)   // 32768

__device__ __forceinline__ float sigmoidf_fast(float x) { return 1.f / (1.f + __expf(-x)); }
__device__ __forceinline__ float tanhf_fast(float x) { return 1.f - 2.f / (__expf(2.f * x) + 1.f); }

// VALU-only neighbor-pair swap (lanes 0<->1, 2<->3, ...): DPP quad_perm(1,0,3,2)
__device__ __forceinline__ float swap_pair(float x) {
    int yi = __builtin_amdgcn_mov_dpp(__float_as_int(x), 0xB1, 0xF, 0xF, true);
    return __int_as_float(yi);
}

// ---------------------------------------------------------------------------
// Fused kernel A+B. Blocks [0,1024): w = softmax(Ek[q] . Mk^T)  (32 rows/blk)
//                   Blocks [1024,3072): e/a = sig/tanh(Ev[x]@We|Wa) (16 rows)
// ---------------------------------------------------------------------------
__global__ __launch_bounds__(128) void kAB(const int* __restrict__ q,
                                           const int* __restrict__ r,
                                           const float* __restrict__ Ek,
                                           const float* __restrict__ Ev,
                                           const float* __restrict__ Mk,
                                           const float* __restrict__ We,
                                           const float* __restrict__ be,
                                           const float* __restrict__ Wa,
                                           const float* __restrict__ ba,
                                           float* __restrict__ w_out,
                                           float* __restrict__ e_out,
                                           float* __restrict__ a_out) {
    __shared__ __align__(16) float smem[DIM * 65 + 2 * DIM];
    const int tid = threadIdx.x;

    if (blockIdx.x < 1024) {
        // ---------------- kA role ----------------
        float* MkT = smem;                  // [DIM][65]
        float* kbuf = smem + DIM * 65;      // [2][DIM]

        #pragma unroll
        for (int it = 0; it < 64; ++it) {
            int idx = it * 128 + tid;
            int m = idx >> 7, i = idx & 127;
            MkT[i * 65 + m] = Mk[m * DIM + i];
        }
        __syncthreads();

        const int wv = tid >> 6;
        const int lane = tid & 63;
        const int base = blockIdx.x * 32;

        for (int it = 0; it < 16; ++it) {
            int rr = base + it * 2 + wv;
            int qv = q[rr];
            kbuf[wv * DIM + lane]      = Ek[(size_t)qv * DIM + lane];
            kbuf[wv * DIM + lane + 64] = Ek[(size_t)qv * DIM + lane + 64];
            __syncthreads();

            float s = 0.f;
            #pragma unroll 8
            for (int i = 0; i < DIM; ++i)
                s = fmaf(kbuf[wv * DIM + i], MkT[i * 65 + lane], s);

            float mx = s;
            #pragma unroll
            for (int o = 32; o >= 1; o >>= 1) mx = fmaxf(mx, __shfl_xor(mx, o));
            float ex = __expf(s - mx);
            float sum = ex;
            #pragma unroll
            for (int o = 32; o >= 1; o >>= 1) sum += __shfl_xor(sum, o);

            w_out[(size_t)rr * MM + lane] = ex / sum;
            __syncthreads();
        }
    } else {
        // ---------------- kB role ----------------
        float* vbufT = smem;                // [DIM][20], 16B-aligned rows
        const int base = (blockIdx.x - 1024) * 16;

        #pragma unroll
        for (int rr = 0; rr < 16; ++rr) {
            int row = base + rr;
            int x = q[row] + NUM_C * r[row];
            vbufT[tid * 20 + rr] = Ev[(size_t)x * DIM + tid];
        }
        __syncthreads();

        float eacc[16], aacc[16];
        #pragma unroll
        for (int rr = 0; rr < 16; ++rr) { eacc[rr] = 0.f; aacc[rr] = 0.f; }

        #pragma unroll 4
        for (int i = 0; i < DIM; ++i) {
            float we = We[i * DIM + tid];
            float wa = Wa[i * DIM + tid];
            const float4* vp = reinterpret_cast<const float4*>(&vbufT[i * 20]);
            float4 v0 = vp[0], v1 = vp[1], v2 = vp[2], v3 = vp[3];
            float vr[16] = {v0.x, v0.y, v0.z, v0.w, v1.x, v1.y, v1.z, v1.w,
                            v2.x, v2.y, v2.z, v2.w, v3.x, v3.y, v3.z, v3.w};
            #pragma unroll
            for (int rr = 0; rr < 16; ++rr) {
                eacc[rr] = fmaf(vr[rr], we, eacc[rr]);
                aacc[rr] = fmaf(vr[rr], wa, aacc[rr]);
            }
        }

        float bev = be[tid], bav = ba[tid];
        #pragma unroll
        for (int rr = 0; rr < 16; ++rr) {
            int row = base + rr;
            e_out[(size_t)row * DIM + tid] = sigmoidf_fast(eacc[rr] + bev);
            a_out[(size_t)row * DIM + tid] = tanhf_fast(aacc[rr] + bav);
        }
    }
}

// ---------------------------------------------------------------------------
// Kernel C: all-register scan, no LDS, no barriers.
// Block (g,b): m-slice [g*16, g*16+16). Thread t: d = t>>1, p = t&1 owns 8 m.
// e/a: 16-step register tiles, double-buffered (loads issued one tile ahead).
// w: depth-4 register ring (wave-broadcast loads).
// Output: atomicAdd into read_buf[b][t][d] (pre-zeroed).
// ---------------------------------------------------------------------------
__device__ __forceinline__ void kc_load_tile(const float* ep, const float* ap,
                                             int c, float (&eR)[16], float (&aR)[16]) {
    if (c < LL / 16) {
        #pragma unroll
        for (int u = 0; u < 16; ++u) {
            eR[u] = ep[(size_t)(c * 16 + u) * DIM];
            aR[u] = ap[(size_t)(c * 16 + u) * DIM];
        }
    }
}

__device__ __forceinline__ void kc_scan_tile(int c, int p, float (&Mv)[8],
                                             const float (&eR)[16], const float (&aR)[16],
                                             float4 (&wR)[4][2],
                                             const float* wp, float* rp) {
    #pragma unroll
    for (int u = 0; u < 16; ++u) {
        const int t = c * 16 + u;
        const int slot = u & 3;                 // 16 % 4 == 0 -> compile-time
        float4 w0 = wR[slot][0], w1 = wR[slot][1];
        if (t + 4 < LL) {                       // prefetch w for t+4
            wR[slot][0] = *reinterpret_cast<const float4*>(wp + (size_t)(t + 4) * MM);
            wR[slot][1] = *reinterpret_cast<const float4*>(wp + (size_t)(t + 4) * MM + 4);
        }
        float e_c = eR[u], a_c = aR[u];
        float wv[8] = {w0.x, w0.y, w0.z, w0.w, w1.x, w1.y, w1.z, w1.w};
        float part = 0.f;
        #pragma unroll
        for (int j = 0; j < 8; ++j) {
            float old = Mv[j];
            part = fmaf(wv[j], old, part);             // read BEFORE update
            Mv[j] = fmaf(wv[j], fmaf(-old, e_c, a_c), old);
        }
        part += swap_pair(part);
        if (p == 0) atomicAdd(rp + (size_t)t * DIM, part);
    }
}

__global__ __launch_bounds__(256) void kC(const float* __restrict__ Mv0,
                                          const float* __restrict__ w_in,
                                          const float* __restrict__ e_in,
                                          const float* __restrict__ a_in,
                                          float* __restrict__ read_buf) {
    const int tid = threadIdx.x;
    const int p = tid & 1;
    const int d = tid >> 1;
    const int g = blockIdx.x, b = blockIdx.y;
    const int m0 = g * 16 + p * 8;

    float Mv[8];
    #pragma unroll
    for (int j = 0; j < 8; ++j)
        Mv[j] = Mv0[(m0 + j) * DIM + d];

    const float* wp = w_in + (size_t)b * LL * MM + m0;
    const float* ep = e_in + (size_t)b * LL * DIM + d;
    const float* ap = a_in + (size_t)b * LL * DIM + d;
    float* rp = read_buf + (size_t)b * LL * DIM + d;

    float eR0[16], aR0[16], eR1[16], aR1[16];
    float4 wR[4][2];

    kc_load_tile(ep, ap, 0, eR0, aR0);
    #pragma unroll
    for (int u = 0; u < 4; ++u) {
        wR[u][0] = *reinterpret_cast<const float4*>(wp + (size_t)u * MM);
        wR[u][1] = *reinterpret_cast<const float4*>(wp + (size_t)u * MM + 4);
    }

    for (int c = 0; c < LL / 16; c += 2) {
        kc_load_tile(ep, ap, c + 1, eR1, aR1);   // next tile in flight
        kc_scan_tile(c, p, Mv, eR0, aR0, wR, wp, rp);
        kc_load_tile(ep, ap, c + 2, eR0, aR0);
        kc_scan_tile(c + 1, p, Mv, eR1, aR1, wR, wp, rp);
    }
}

// ---------------------------------------------------------------------------
// Kernel D: f = tanh([read,k]@Wf + bf); p = sigmoid(f@Wp+bp)
// 128 threads, 16 rows per block; x transposed in LDS stride 20.
// ---------------------------------------------------------------------------
__global__ __launch_bounds__(128) void kD(const int* __restrict__ q,
                                          const float* __restrict__ Ek,
                                          const float* __restrict__ Wf,
                                          const float* __restrict__ bfv,
                                          const float* __restrict__ Wp,
                                          const float* __restrict__ bp,
                                          const float* __restrict__ read_buf,
                                          float* __restrict__ out) {
    __shared__ __align__(16) float xbufT[2 * DIM][20];
    __shared__ float fbuf[16][DIM];
    __shared__ float sbuf[16][8];
    const int tid = threadIdx.x;
    const int base = blockIdx.x * 16;

    #pragma unroll
    for (int rr = 0; rr < 16; ++rr) {
        int row = base + rr;
        xbufT[tid][rr] = read_buf[(size_t)row * DIM + tid];
        xbufT[DIM + tid][rr] = Ek[(size_t)q[row] * DIM + tid];
    }
    __syncthreads();

    float facc[16];
    #pragma unroll
    for (int rr = 0; rr < 16; ++rr) facc[rr] = 0.f;

    #pragma unroll 4
    for (int i = 0; i < 2 * DIM; ++i) {
        float wf = Wf[i * DIM + tid];
        const float4* xp = reinterpret_cast<const float4*>(&xbufT[i][0]);
        float4 x0 = xp[0], x1 = xp[1], x2 = xp[2], x3 = xp[3];
        float xr[16] = {x0.x, x0.y, x0.z, x0.w, x1.x, x1.y, x1.z, x1.w,
                        x2.x, x2.y, x2.z, x2.w, x3.x, x3.y, x3.z, x3.w};
        #pragma unroll
        for (int rr = 0; rr < 16; ++rr)
            facc[rr] = fmaf(xr[rr], wf, facc[rr]);
    }

    float bfs = bfv[tid];
    float wpv = Wp[tid];
    #pragma unroll
    for (int rr = 0; rr < 16; ++rr)
        fbuf[rr][tid] = tanhf_fast(facc[rr] + bfs) * wpv;
    __syncthreads();

    {
        int rr = tid >> 3, j = tid & 7;
        float s = 0.f;
        #pragma unroll
        for (int i = 0; i < 16; ++i) s += fbuf[rr][j + 8 * i];
        sbuf[rr][j] = s;
    }
    __syncthreads();
    if (tid < 16) {
        float s = bp[0];
        #pragma unroll
        for (int j = 0; j < 8; ++j) s += sbuf[tid][j];
        out[base + tid] = sigmoidf_fast(s);
    }
}

// ---------------------------------------------------------------------------
extern "C" void kernel_launch(void* const* d_in, const int* in_sizes, int n_in,
                              void* d_out, int out_size, void* d_ws, size_t ws_size,
                              hipStream_t stream) {
    const int*   q   = (const int*)d_in[0];
    const int*   r   = (const int*)d_in[1];
    const float* Ek  = (const float*)d_in[2];
    const float* Ev  = (const float*)d_in[3];
    const float* Mk  = (const float*)d_in[4];
    const float* Mv0 = (const float*)d_in[5];
    const float* We  = (const float*)d_in[6];
    const float* be  = (const float*)d_in[7];
    const float* Wa  = (const float*)d_in[8];
    const float* ba  = (const float*)d_in[9];
    const float* Wf  = (const float*)d_in[10];
    const float* bfv = (const float*)d_in[11];
    const float* Wp  = (const float*)d_in[12];
    const float* bp  = (const float*)d_in[13];
    float* out = (float*)d_out;

    float* ws    = (float*)d_ws;
    float* w_buf = ws;                                   // NROWS*64  floats (8 MB)
    float* e_buf = w_buf + (size_t)NROWS * MM;           // NROWS*128 floats (16 MB)
    float* a_buf = e_buf + (size_t)NROWS * DIM;          // 16 MB
    float* read  = a_buf + (size_t)NROWS * DIM;          // 16 MB

    // read buffer must start at zero (atomicAdd accumulates into it)
    hipMemsetAsync(read, 0, (size_t)NROWS * DIM * sizeof(float), stream);

    kAB<<<dim3(3072), 128, 0, stream>>>(q, r, Ek, Ev, Mk, We, be, Wa, ba,
                                        w_buf, e_buf, a_buf);
    kC<<<dim3(4, BB), 256, 0, stream>>>(Mv0, w_buf, e_buf, a_buf, read);
    kD<<<dim3(NROWS / 16), 128, 0, stream>>>(q, Ek, Wf, bfv, Wp, bp, read, out);
}

// Round 5
// 262.356 us; speedup vs baseline: 1.5147x; 1.1272x over previous
//
#include <hip/hip_runtime.h>
#include <hip/hip_bf16.h>

#define NUM_C 1000
#define DIM   128
#define MM    64
#define BB    64
#define LL    512
#define NROWS (BB * LL)   // 32768

__device__ __forceinline__ float sigmoidf_fast(float x) { return 1.f / (1.f + __expf(-x)); }
__device__ __forceinline__ float tanhf_fast(float x) { return 1.f - 2.f / (__expf(2.f * x) + 1.f); }

// VALU-only neighbor-pair swap (lanes 0<->1, 2<->3, ...): DPP quad_perm(1,0,3,2)
__device__ __forceinline__ float swap_pair(float x) {
    int yi = __builtin_amdgcn_mov_dpp(__float_as_int(x), 0xB1, 0xF, 0xF, true);
    return __int_as_float(yi);
}

__device__ __forceinline__ float dot4(float4 a, float4 b, float acc) {
    return fmaf(a.x, b.x, fmaf(a.y, b.y, fmaf(a.z, b.z, fmaf(a.w, b.w, acc))));
}

// ---------------------------------------------------------------------------
// Kernel A: w[b,l,m] = softmax_m( k . Mk[m] ),  k = Ek[q[b,l]]
// 256 threads = 4 waves; each wave computes 4 rows; lane = m.
// Mk staged in LDS as float4 [i4][m]: lane-stride-16B b128 reads (conflict-
// free, m97 pattern). k rows read via wave-uniform scalar loads (SGPR
// operands -> zero LDS traffic in the dot loop).
// ---------------------------------------------------------------------------
__global__ __launch_bounds__(256) void kA(const int* __restrict__ q,
                                          const float* __restrict__ Ek,
                                          const float* __restrict__ Mk,
                                          float* __restrict__ w_out) {
    __shared__ __align__(16) float4 Mk4[32][64];   // 32 KB: [i4][m]
    const int tid = threadIdx.x;
    const int lane = tid & 63;
    const int wv = tid >> 6;

    // stage: thread (wv,lane): m = lane, i4 = wv + 4j  (global reads L1/L2-cached)
    #pragma unroll
    for (int j = 0; j < 8; ++j) {
        int i4 = wv + 4 * j;
        Mk4[i4][lane] = *reinterpret_cast<const float4*>(Mk + lane * DIM + i4 * 4);
    }
    __syncthreads();

    // wave-uniform row base -> scalar loads for q and k
    const int rb = __builtin_amdgcn_readfirstlane(blockIdx.x * 16 + wv * 4);
    const float* k0 = Ek + (size_t)q[rb + 0] * DIM;
    const float* k1 = Ek + (size_t)q[rb + 1] * DIM;
    const float* k2 = Ek + (size_t)q[rb + 2] * DIM;
    const float* k3 = Ek + (size_t)q[rb + 3] * DIM;

    float acc[4] = {0.f, 0.f, 0.f, 0.f};
    #pragma unroll 8
    for (int i4 = 0; i4 < 32; ++i4) {
        float4 mk = Mk4[i4][lane];
        float4 a0 = *reinterpret_cast<const float4*>(k0 + i4 * 4);
        float4 a1 = *reinterpret_cast<const float4*>(k1 + i4 * 4);
        float4 a2 = *reinterpret_cast<const float4*>(k2 + i4 * 4);
        float4 a3 = *reinterpret_cast<const float4*>(k3 + i4 * 4);
        acc[0] = dot4(a0, mk, acc[0]);
        acc[1] = dot4(a1, mk, acc[1]);
        acc[2] = dot4(a2, mk, acc[2]);
        acc[3] = dot4(a3, mk, acc[3]);
    }

    #pragma unroll
    for (int rr = 0; rr < 4; ++rr) {
        float s = acc[rr];
        float mx = s;
        #pragma unroll
        for (int o = 32; o >= 1; o >>= 1) mx = fmaxf(mx, __shfl_xor(mx, o));
        float ex = __expf(s - mx);
        float sum = ex;
        #pragma unroll
        for (int o = 32; o >= 1; o >>= 1) sum += __shfl_xor(sum, o);
        w_out[(size_t)(rb + rr) * MM + lane] = ex / sum;
    }
}

// ---------------------------------------------------------------------------
// Kernel B: e = sigmoid(v@We+be), a = tanh(v@Wa+ba),  v = Ev[q+1000*r]
// 128 threads, 16 rows per block; lean LDS (10 KB) for high residency.
// ---------------------------------------------------------------------------
__global__ __launch_bounds__(128) void kB(const int* __restrict__ q,
                                          const int* __restrict__ r,
                                          const float* __restrict__ Ev,
                                          const float* __restrict__ We,
                                          const float* __restrict__ be,
                                          const float* __restrict__ Wa,
                                          const float* __restrict__ ba,
                                          float* __restrict__ e_out,
                                          float* __restrict__ a_out) {
    __shared__ __align__(16) float vbufT[DIM][20];
    const int tid = threadIdx.x;
    const int base = blockIdx.x * 16;

    #pragma unroll
    for (int rr = 0; rr < 16; ++rr) {
        int row = base + rr;
        int x = q[row] + NUM_C * r[row];
        vbufT[tid][rr] = Ev[(size_t)x * DIM + tid];
    }
    __syncthreads();

    float eacc[16], aacc[16];
    #pragma unroll
    for (int rr = 0; rr < 16; ++rr) { eacc[rr] = 0.f; aacc[rr] = 0.f; }

    #pragma unroll 4
    for (int i = 0; i < DIM; ++i) {
        float we = We[i * DIM + tid];
        float wa = Wa[i * DIM + tid];
        const float4* vp = reinterpret_cast<const float4*>(&vbufT[i][0]);
        float4 v0 = vp[0], v1 = vp[1], v2 = vp[2], v3 = vp[3];
        float vr[16] = {v0.x, v0.y, v0.z, v0.w, v1.x, v1.y, v1.z, v1.w,
                        v2.x, v2.y, v2.z, v2.w, v3.x, v3.y, v3.z, v3.w};
        #pragma unroll
        for (int rr = 0; rr < 16; ++rr) {
            eacc[rr] = fmaf(vr[rr], we, eacc[rr]);
            aacc[rr] = fmaf(vr[rr], wa, aacc[rr]);
        }
    }

    float bev = be[tid], bav = ba[tid];
    #pragma unroll
    for (int rr = 0; rr < 16; ++rr) {
        int row = base + rr;
        e_out[(size_t)row * DIM + tid] = sigmoidf_fast(eacc[rr] + bev);
        a_out[(size_t)row * DIM + tid] = tanhf_fast(aacc[rr] + bav);
    }
}

// ---------------------------------------------------------------------------
// Kernel C: all-register scan, no LDS/barriers/atomics.
// Block (g,b): m-slice [g*16, g*16+16). Thread: d = t>>1, p = t&1 owns 8 m.
// e/a: 16-step register tiles double-buffered; w: depth-8 register ring
// (~270 cyc prefetch distance > L2 latency). Plain stores to per-g partial.
// ---------------------------------------------------------------------------
__device__ __forceinline__ void kc_load_tile(const float* ep, const float* ap,
                                             int c, float (&eR)[16], float (&aR)[16]) {
    if (c < LL / 16) {
        #pragma unroll
        for (int u = 0; u < 16; ++u) {
            eR[u] = ep[(size_t)(c * 16 + u) * DIM];
            aR[u] = ap[(size_t)(c * 16 + u) * DIM];
        }
    }
}

__device__ __forceinline__ void kc_scan_tile(int c, int p, float (&Mv)[8],
                                             const float (&eR)[16], const float (&aR)[16],
                                             float4 (&wR)[8][2],
                                             const float* wp, float* pr) {
    #pragma unroll
    for (int u = 0; u < 16; ++u) {
        const int t = c * 16 + u;
        const int slot = u & 7;                 // (c*16)&7==0 -> compile-time
        float4 w0 = wR[slot][0], w1 = wR[slot][1];
        if (t + 8 < LL) {                       // prefetch w for t+8
            wR[slot][0] = *reinterpret_cast<const float4*>(wp + (size_t)(t + 8) * MM);
            wR[slot][1] = *reinterpret_cast<const float4*>(wp + (size_t)(t + 8) * MM + 4);
        }
        float e_c = eR[u], a_c = aR[u];
        float wv[8] = {w0.x, w0.y, w0.z, w0.w, w1.x, w1.y, w1.z, w1.w};
        float part = 0.f;
        #pragma unroll
        for (int j = 0; j < 8; ++j) {
            float old = Mv[j];
            part = fmaf(wv[j], old, part);             // read BEFORE update
            Mv[j] = fmaf(wv[j], fmaf(-old, e_c, a_c), old);
        }
        part += swap_pair(part);
        if (p == 0) pr[(size_t)t * DIM] = part;
    }
}

__global__ __launch_bounds__(256) void kC(const float* __restrict__ Mv0,
                                          const float* __restrict__ w_in,
                                          const float* __restrict__ e_in,
                                          const float* __restrict__ a_in,
                                          float* __restrict__ partial) {
    const int tid = threadIdx.x;
    const int p = tid & 1;
    const int d = tid >> 1;
    const int g = blockIdx.x, b = blockIdx.y;
    const int m0 = g * 16 + p * 8;

    float Mv[8];
    #pragma unroll
    for (int j = 0; j < 8; ++j)
        Mv[j] = Mv0[(m0 + j) * DIM + d];

    const float* wp = w_in + (size_t)b * LL * MM + m0;
    const float* ep = e_in + (size_t)b * LL * DIM + d;
    const float* ap = a_in + (size_t)b * LL * DIM + d;
    float* pr = partial + ((size_t)(g * BB + b) * LL) * DIM + d;

    float eR0[16], aR0[16], eR1[16], aR1[16];
    float4 wR[8][2];

    kc_load_tile(ep, ap, 0, eR0, aR0);
    #pragma unroll
    for (int u = 0; u < 8; ++u) {
        wR[u][0] = *reinterpret_cast<const float4*>(wp + (size_t)u * MM);
        wR[u][1] = *reinterpret_cast<const float4*>(wp + (size_t)u * MM + 4);
    }

    for (int c = 0; c < LL / 16; c += 2) {
        kc_load_tile(ep, ap, c + 1, eR1, aR1);   // next tile in flight
        kc_scan_tile(c, p, Mv, eR0, aR0, wR, wp, pr);
        kc_load_tile(ep, ap, c + 2, eR0, aR0);
        kc_scan_tile(c + 1, p, Mv, eR1, aR1, wR, wp, pr);
    }
}

// ---------------------------------------------------------------------------
// Kernel D: read = sum_g partial; f = tanh([read,k]@Wf + bf); p = sigmoid(f@Wp+bp)
// 128 threads, 16 rows per block; x transposed in LDS stride 20.
// ---------------------------------------------------------------------------
__global__ __launch_bounds__(128) void kD(const int* __restrict__ q,
                                          const float* __restrict__ Ek,
                                          const float* __restrict__ Wf,
                                          const float* __restrict__ bfv,
                                          const float* __restrict__ Wp,
                                          const float* __restrict__ bp,
                                          const float* __restrict__ partial,
                                          float* __restrict__ out) {
    __shared__ __align__(16) float xbufT[2 * DIM][20];
    __shared__ float fbuf[16][DIM];
    __shared__ float sbuf[16][8];
    const int tid = threadIdx.x;
    const int base = blockIdx.x * 16;

    #pragma unroll
    for (int rr = 0; rr < 16; ++rr) {
        int row = base + rr;
        float rd = 0.f;
        #pragma unroll
        for (int g = 0; g < 4; ++g)
            rd += partial[(size_t)g * NROWS * DIM + (size_t)row * DIM + tid];
        xbufT[tid][rr] = rd;
        xbufT[DIM + tid][rr] = Ek[(size_t)q[row] * DIM + tid];
    }
    __syncthreads();

    float facc[16];
    #pragma unroll
    for (int rr = 0; rr < 16; ++rr) facc[rr] = 0.f;

    #pragma unroll 4
    for (int i = 0; i < 2 * DIM; ++i) {
        float wf = Wf[i * DIM + tid];
        const float4* xp = reinterpret_cast<const float4*>(&xbufT[i][0]);
        float4 x0 = xp[0], x1 = xp[1], x2 = xp[2], x3 = xp[3];
        float xr[16] = {x0.x, x0.y, x0.z, x0.w, x1.x, x1.y, x1.z, x1.w,
                        x2.x, x2.y, x2.z, x2.w, x3.x, x3.y, x3.z, x3.w};
        #pragma unroll
        for (int rr = 0; rr < 16; ++rr)
            facc[rr] = fmaf(xr[rr], wf, facc[rr]);
    }

    float bfs = bfv[tid];
    float wpv = Wp[tid];
    #pragma unroll
    for (int rr = 0; rr < 16; ++rr)
        fbuf[rr][tid] = tanhf_fast(facc[rr] + bfs) * wpv;
    __syncthreads();

    {
        int rr = tid >> 3, j = tid & 7;
        float s = 0.f;
        #pragma unroll
        for (int i = 0; i < 16; ++i) s += fbuf[rr][j + 8 * i];
        sbuf[rr][j] = s;
    }
    __syncthreads();
    if (tid < 16) {
        float s = bp[0];
        #pragma unroll
        for (int j = 0; j < 8; ++j) s += sbuf[tid][j];
        out[base + tid] = sigmoidf_fast(s);
    }
}

// ---------------------------------------------------------------------------
extern "C" void kernel_launch(void* const* d_in, const int* in_sizes, int n_in,
                              void* d_out, int out_size, void* d_ws, size_t ws_size,
                              hipStream_t stream) {
    const int*   q   = (const int*)d_in[0];
    const int*   r   = (const int*)d_in[1];
    const float* Ek  = (const float*)d_in[2];
    const float* Ev  = (const float*)d_in[3];
    const float* Mk  = (const float*)d_in[4];
    const float* Mv0 = (const float*)d_in[5];
    const float* We  = (const float*)d_in[6];
    const float* be  = (const float*)d_in[7];
    const float* Wa  = (const float*)d_in[8];
    const float* ba  = (const float*)d_in[9];
    const float* Wf  = (const float*)d_in[10];
    const float* bfv = (const float*)d_in[11];
    const float* Wp  = (const float*)d_in[12];
    const float* bp  = (const float*)d_in[13];
    float* out = (float*)d_out;

    float* ws    = (float*)d_ws;
    float* w_buf = ws;                                   // 8 MB
    float* e_buf = w_buf + (size_t)NROWS * MM;           // 16 MB
    float* a_buf = e_buf + (size_t)NROWS * DIM;          // 16 MB
    float* part  = a_buf + (size_t)NROWS * DIM;          // 4 x 16 MB

    kA<<<dim3(NROWS / 16), 256, 0, stream>>>(q, Ek, Mk, w_buf);
    kB<<<dim3(NROWS / 16), 128, 0, stream>>>(q, r, Ev, We, be, Wa, ba, e_buf, a_buf);
    kC<<<dim3(4, BB), 256, 0, stream>>>(Mv0, w_buf, e_buf, a_buf, part);
    kD<<<dim3(NROWS / 16), 128, 0, stream>>>(q, Ek, Wf, bfv, Wp, bp, part, out);
}